// Round 13
// baseline (287.658 us; speedup 1.0000x reference)
//
#include <hip/hip_runtime.h>
#include <math.h>

// Problem constants (match reference)
#define B_TOK 16384
#define H_DIM 2048
#define NE    8
#define TOPK  2
#define HFD   512

#define BK 32
#define NKSTEP (H_DIM / BK)   // 64
#define PTMAX 129
#define PROWS 33792           // padded P rows total (8 experts, 128-padded)

// Workspace layout (bytes)
static constexpr size_t OFF_COUNTS = 0;
static constexpr size_t OFF_CBASE  = 128;
static constexpr size_t OFF_BUCKET = 1024;        // 512 KB
static constexpr size_t OFF_WSLOT  = 525312;      // 128 KB
static constexpr size_t OFF_ROUTE  = 656384;      // 64 KB
static constexpr size_t OFF_INV    = 721920;      // 128 KB
static constexpr size_t OFF_WGT    = 1u << 20;    // 512 KB
static constexpr size_t OFF_P4     = 1572864;     // 528 KB
static constexpr size_t OFF_W1Q    = 4u << 20;    // 16 MB -> ends 20 MB
static constexpr size_t OFF_XGT    = 20971520;    // 33792 rows * 4 KB = 132 MB
// total ws ~153 MB

typedef short bfrag __attribute__((ext_vector_type(8)));   // 8 bf16 (4 VGPR)
typedef float facc  __attribute__((ext_vector_type(16)));  // 32x32 accum

__device__ inline unsigned short f2bf(float f) {
    union { float f; unsigned u; } v; v.f = f;
    unsigned r = v.u + 0x7FFFu + ((v.u >> 16) & 1u);
    return (unsigned short)(r >> 16);
}
__device__ inline unsigned pack2(float lo, float hi) {
    return (unsigned)f2bf(lo) | ((unsigned)f2bf(hi) << 16);
}

__device__ __forceinline__ void gload_lds16(const void* g, void* l) {
    __builtin_amdgcn_global_load_lds(
        (const __attribute__((address_space(1))) unsigned int*)g,
        (__attribute__((address_space(3))) unsigned int*)l, 16, 0, 0);
}

// ---------------------------------------------------------------------------
// Transpose gate weights: Wg [H][E] -> 8 replicas of WgT [E][H].
// ---------------------------------------------------------------------------
__global__ __launch_bounds__(256)
void wg_transpose_kernel(const float* __restrict__ Wg,
                         float* __restrict__ WgT)
{
    const int t = threadIdx.x;
    #pragma unroll
    for (int rep = 0; rep < H_DIM / 256; ++rep) {
        const int h = rep * 256 + t;
        const float4 a = *reinterpret_cast<const float4*>(Wg + (size_t)h * NE);
        const float4 b = *reinterpret_cast<const float4*>(Wg + (size_t)h * NE + 4);
        #pragma unroll
        for (int rr = 0; rr < 8; ++rr) {
            float* W = WgT + (size_t)rr * (NE * H_DIM);
            W[0 * H_DIM + h] = a.x;  W[1 * H_DIM + h] = a.y;
            W[2 * H_DIM + h] = a.z;  W[3 * H_DIM + h] = a.w;
            W[4 * H_DIM + h] = b.x;  W[5 * H_DIM + h] = b.y;
            W[6 * H_DIM + h] = b.z;  W[7 * H_DIM + h] = b.w;
        }
    }
}

// ---------------------------------------------------------------------------
// Prep W1: [E][H][HF] fp32 -> per-(e, f-quarter) k-slot-major bf16 images:
//   W1q[(e*4+fq)*64 + kstep][slot(4)][fl(128)][j(8)]  (8 KB per image)
// k = kstep*32 + slot*8 + j, f = fq*128 + fl.
// ---------------------------------------------------------------------------
__global__ __launch_bounds__(256)
void prep_w1_kernel(const float* __restrict__ W1,
                    unsigned short* __restrict__ W1q)
{
    const int e     = blockIdx.x >> 6;
    const int kstep = blockIdx.x & 63;
    const int tid   = threadIdx.x;

    const float* src = W1 + ((size_t)e * H_DIM + kstep * BK) * HFD;

    #pragma unroll
    for (int slot = 0; slot < 4; ++slot) {
        #pragma unroll
        for (int half = 0; half < 2; ++half) {
            const int f  = half * 256 + tid;
            const int fq = f >> 7;
            const int fl = f & 127;
            float v[8];
            #pragma unroll
            for (int j = 0; j < 8; ++j)
                v[j] = src[(size_t)(slot * 8 + j) * HFD + f];
            uint4 p;
            p.x = pack2(v[0], v[1]); p.y = pack2(v[2], v[3]);
            p.z = pack2(v[4], v[5]); p.w = pack2(v[6], v[7]);
            *reinterpret_cast<uint4*>(
                W1q + ((size_t)((e * 4 + fq) * 64 + kstep)) * 4096
                    + (slot * 128 + fl) * 8) = p;
        }
    }
}

// ---------------------------------------------------------------------------
// Gate logits: 256 blocks x 64 tokens; WgT staged once into LDS.
// ---------------------------------------------------------------------------
__global__ __launch_bounds__(256)
void gate_logits_kernel(const float* __restrict__ x,
                        const float* __restrict__ WgT,
                        const float* __restrict__ bg,
                        float* __restrict__ out_logits,
                        float* __restrict__ wslot,
                        int*   __restrict__ route)
{
    __shared__ float Wlds[NE * H_DIM];   // 64 KB

    const int tid = threadIdx.x;
    const float* Wsrc = WgT + (size_t)(blockIdx.x & 7) * (NE * H_DIM);
    #pragma unroll
    for (int i = 0; i < (NE * H_DIM) / (256 * 4); ++i) {
        const int idx = (i * 256 + tid) * 4;
        *reinterpret_cast<float4*>(&Wlds[idx]) =
            *reinterpret_cast<const float4*>(Wsrc + idx);
    }
    __syncthreads();

    const int w = tid >> 6, l = tid & 63;
    const int tbase = blockIdx.x * 64 + w * 16;

    for (int pass = 0; pass < 4; ++pass) {
        const int t0 = tbase + pass * 4;
        float acc[4][NE];
        #pragma unroll
        for (int j = 0; j < 4; ++j)
            #pragma unroll
            for (int e = 0; e < NE; ++e) acc[j][e] = 0.f;

        for (int i = 0; i < 8; ++i) {
            const int h = i * 256 + 4 * l;
            float4 xv[4];
            #pragma unroll
            for (int j = 0; j < 4; ++j)
                xv[j] = *reinterpret_cast<const float4*>(
                    x + (size_t)(t0 + j) * H_DIM + h);
            #pragma unroll
            for (int e = 0; e < NE; ++e) {
                const float4 wv = *reinterpret_cast<const float4*>(&Wlds[e * H_DIM + h]);
                #pragma unroll
                for (int j = 0; j < 4; ++j)
                    acc[j][e] += xv[j].x * wv.x + xv[j].y * wv.y
                               + xv[j].z * wv.z + xv[j].w * wv.w;
            }
        }

        #pragma unroll
        for (int j = 0; j < 4; ++j)
            #pragma unroll
            for (int e = 0; e < NE; ++e)
                #pragma unroll
                for (int off = 32; off > 0; off >>= 1)
                    acc[j][e] += __shfl_xor(acc[j][e], off, 64);

        if (l == 0) {
            #pragma unroll
            for (int j = 0; j < 4; ++j) {
                const int tok = t0 + j;
                float lg[NE];
                #pragma unroll
                for (int e = 0; e < NE; ++e) lg[e] = acc[j][e] + bg[e];

                float4* lo = reinterpret_cast<float4*>(out_logits + (size_t)tok * NE);
                lo[0] = make_float4(lg[0], lg[1], lg[2], lg[3]);
                lo[1] = make_float4(lg[4], lg[5], lg[6], lg[7]);

                int i0 = 0; float v0 = lg[0];
                #pragma unroll
                for (int e = 1; e < NE; ++e)
                    if (lg[e] > v0) { v0 = lg[e]; i0 = e; }
                int i1 = -1; float v1 = -3.4e38f;
                #pragma unroll
                for (int e = 0; e < NE; ++e)
                    if (e != i0 && lg[e] > v1) { v1 = lg[e]; i1 = e; }

                const float w0 = 1.f / (1.f + expf(v1 - v0));
                wslot[tok * 2]     = w0;
                wslot[tok * 2 + 1] = 1.f - w0;
                route[tok] = i0 | (i1 << 8);
            }
        }
    }
}

// ---------------------------------------------------------------------------
// Route/bucket: LDS-aggregated histogram; 8 global atomics per block.
// ---------------------------------------------------------------------------
__global__ __launch_bounds__(1024)
void route_kernel(const int* __restrict__ route,
                  int* __restrict__ counts,
                  int* __restrict__ bucket)
{
    __shared__ int lcnt[NE];
    __shared__ int lbase[NE];
    const int tid = threadIdx.x;
    const int tok = blockIdx.x * 1024 + tid;

    if (tid < NE) lcnt[tid] = 0;
    __syncthreads();

    const int rt = route[tok];
    const int i0 = rt & 255;
    const int i1 = rt >> 8;
    const int r0 = atomicAdd(&lcnt[i0], 1);
    const int r1 = atomicAdd(&lcnt[i1], 1);
    __syncthreads();

    if (tid < NE) lbase[tid] = atomicAdd(&counts[tid], lcnt[tid]);
    __syncthreads();

    bucket[i0 * B_TOK + lbase[i0] + r0] = tok * 2;
    bucket[i1 * B_TOK + lbase[i1] + r1] = tok * 2 + 1;
}

// ---------------------------------------------------------------------------
// Prefix: cbase[e] = row base; cpad[e] = count padded to 128.
// ---------------------------------------------------------------------------
__global__ void prefix_kernel(const int* __restrict__ counts,
                              int* __restrict__ cbase)
{
    if (threadIdx.x == 0 && blockIdx.x == 0) {
        int acc = 0;
        for (int e = 0; e < NE; ++e) {
            const int cp = ((counts[e] + 127) >> 7) << 7;
            cbase[e]      = acc;
            cbase[NE + e] = cp;
            acc += cp;
        }
    }
}

// ---------------------------------------------------------------------------
// X gather/transpose (r6, proven): per expert e, 64-pos tile, write
//   xgT[cb rows][kstep(64)][slot(4)][pos][j(8)]
// elem offset = cb*2048 + ((kstep*4+slot)*cpad + pos)*8. Coalesced reads of
// x, LDS transpose, 1 KB coalesced stores. Also writes inv[entry].
// ---------------------------------------------------------------------------
__global__ __launch_bounds__(256)
void xgather_kernel(const float* __restrict__ x,
                    const int* __restrict__ bucket,
                    const int* __restrict__ counts,
                    const int* __restrict__ cbase,
                    unsigned short* __restrict__ xgT,
                    int* __restrict__ inv)
{
    const int e    = blockIdx.x & 7;
    const int tile = blockIdx.x >> 3;
    const int n    = counts[e];
    const int pos0 = tile * 64;
    if (pos0 >= n) return;
    const int cb   = cbase[e];
    const size_t cpad = (size_t)cbase[NE + e];
    const int t = threadIdx.x;

    __shared__ int toks[64];
    __shared__ unsigned short T[8][64][8];

    if (t < 64) {
        const int pos = pos0 + t;
        const int entry = bucket[e * B_TOK + min(pos, n - 1)];
        toks[t] = entry >> 1;
        if (pos < n) inv[entry] = cb + pos;
    }
    __syncthreads();

    const int p = t >> 2;
    const int q = t & 3;
    const float* src = x + (size_t)toks[p] * H_DIM + q * 16;
    unsigned short* dstbase = xgT + (size_t)cb * H_DIM;

    for (int kc = 0; kc < 32; ++kc) {
        const float4 v0 = *reinterpret_cast<const float4*>(src + kc * 64);
        const float4 v1 = *reinterpret_cast<const float4*>(src + kc * 64 + 4);
        const float4 v2 = *reinterpret_cast<const float4*>(src + kc * 64 + 8);
        const float4 v3 = *reinterpret_cast<const float4*>(src + kc * 64 + 12);
        uint4 pa, pb;
        pa.x = pack2(v0.x, v0.y); pa.y = pack2(v0.z, v0.w);
        pa.z = pack2(v1.x, v1.y); pa.w = pack2(v1.z, v1.w);
        pb.x = pack2(v2.x, v2.y); pb.y = pack2(v2.z, v2.w);
        pb.z = pack2(v3.x, v3.y); pb.w = pack2(v3.z, v3.w);
        __syncthreads();
        *reinterpret_cast<uint4*>(&T[q * 2][p][0])     = pa;
        *reinterpret_cast<uint4*>(&T[q * 2 + 1][p][0]) = pb;
        __syncthreads();
        #pragma unroll
        for (int g = 0; g < 2; ++g) {
            const int u   = t + g * 256;
            const int s8  = u >> 6;
            const int pp  = u & 63;
            const int kst = 2 * kc + (s8 >> 2);
            const int sl  = s8 & 3;
            *reinterpret_cast<uint4*>(
                dstbase + ((size_t)(kst * 4 + sl) * cpad + pos0 + pp) * 8) =
                *reinterpret_cast<const uint4*>(&T[s8][pp][0]);
        }
    }
}

// ---------------------------------------------------------------------------
// Expert MFMA (operand-swapped): block = (e, f-quarter fq, 128-pos tile).
// Computes P[pos][f] with A = X (per-lane VGPR stream from the coalesced
// xgT image -- NO LDS, no gather in the hot loop) and B = W1 (LDS, 8 KB
// k-slot image per step, canonical stride-16B conflict-free reads).
// 256 thr / 4 waves (wm = pos-half, wn = f-half), acc 2m x 2fh = 4 frags.
// Double-buffered W LDS + double X reg-buffers, counted vmcnt(6), r11's
// 2-barrier skeleton, 17 KB LDS -> 4 blocks/CU. Deterministic P4 writes.
// ---------------------------------------------------------------------------
__global__ __launch_bounds__(256, 4)
void expert_mfma_kernel(const unsigned short* __restrict__ xgT,
                        const unsigned short* __restrict__ W1q,
                        const float* __restrict__ b1,
                        const float* __restrict__ W2,
                        const int* __restrict__ counts,
                        const int* __restrict__ cbase,
                        float* __restrict__ P4)
{
    const int e  = blockIdx.x & 7;
    const int r  = blockIdx.x >> 3;
    const int fq = r & 3;
    const int pt = r >> 2;
    const int n  = counts[e];
    const int pos0 = pt * 128;
    if (pos0 >= n) return;
    const int nt = min(128, n - pos0);
    const int cb = cbase[e];
    const size_t cpad = (size_t)cbase[NE + e];

    __shared__ unsigned short Wlds[2][4096];   // [slot4][fl128][8]  8 KB each
    __shared__ float o_part[2][128];           // [wn][pos]          1 KB

    const int tid = threadIdx.x;
    const int w   = tid >> 6;
    const int l   = tid & 63;
    const int lo5 = l & 31;
    const int hi  = l >> 5;
    const int wm  = w & 1;      // pos half (64 rows)
    const int wn  = w >> 1;     // f half   (64 cols)

    const unsigned short* Wimg = W1q + (size_t)((e * 4 + fq) * 64) * 4096;
    const unsigned short* xg_e = xgT + (size_t)cb * H_DIM;

    // W stage: 8 KB / 256 thr = 2 x 16 B per thread (linear)
    const int wo0 = tid * 8;
    const int wo1 = (256 + tid) * 8;

    // X per-lane rows (A-frag: lane lo5 = pos row, hi = k-slot half)
    const size_t posm0 = (size_t)pos0 + wm * 64 + lo5;
    const size_t posm1 = posm0 + 32;

    facc acc00, acc01, acc10, acc11;   // [m][fh]
    #pragma unroll
    for (int q = 0; q < 16; ++q) {
        acc00[q] = 0.f; acc01[q] = 0.f; acc10[q] = 0.f; acc11[q] = 0.f;
    }

    bfrag xa[2][2], xbv[2][2];   // [m][c]

    #define XLOAD(KK, X) do {                                                  \
        X[0][0] = *reinterpret_cast<const bfrag*>(                             \
            xg_e + (((KK) * 4 + 0 + hi) * cpad + posm0) * 8);                  \
        X[0][1] = *reinterpret_cast<const bfrag*>(                             \
            xg_e + (((KK) * 4 + 2 + hi) * cpad + posm0) * 8);                  \
        X[1][0] = *reinterpret_cast<const bfrag*>(                             \
            xg_e + (((KK) * 4 + 0 + hi) * cpad + posm1) * 8);                  \
        X[1][1] = *reinterpret_cast<const bfrag*>(                             \
            xg_e + (((KK) * 4 + 2 + hi) * cpad + posm1) * 8);                  \
    } while (0)

    #define WSTAGE(KK, B) do {                                                 \
        const unsigned short* ws_ = Wimg + (size_t)(KK) * 4096;                \
        gload_lds16(ws_ + wo0, &Wlds[B][0] + wo0);                             \
        gload_lds16(ws_ + wo1, &Wlds[B][0] + wo1);                             \
    } while (0)

    #define COMPUTE(X, B) do {                                                 \
        _Pragma("unroll")                                                      \
        for (int c = 0; c < 2; ++c) {                                          \
            const int slot = c * 2 + hi;                                       \
            const bfrag wf0 = *reinterpret_cast<const bfrag*>(                 \
                &Wlds[B][(slot * 128 + wn * 64 + lo5) * 8]);                   \
            const bfrag wf1 = *reinterpret_cast<const bfrag*>(                 \
                &Wlds[B][(slot * 128 + wn * 64 + 32 + lo5) * 8]);              \
            acc00 = __builtin_amdgcn_mfma_f32_32x32x16_bf16(X[0][c], wf0, acc00, 0, 0, 0); \
            acc01 = __builtin_amdgcn_mfma_f32_32x32x16_bf16(X[0][c], wf1, acc01, 0, 0, 0); \
            acc10 = __builtin_amdgcn_mfma_f32_32x32x16_bf16(X[1][c], wf0, acc10, 0, 0, 0); \
            acc11 = __builtin_amdgcn_mfma_f32_32x32x16_bf16(X[1][c], wf1, acc11, 0, 0, 0); \
        }                                                                      \
    } while (0)

    XLOAD(0, xa); WSTAGE(0, 0);          // 6 vmem in flight

    for (int kk = 0; kk < NKSTEP; kk += 2) {
        // even step kk: Wlds[0], xa
        if (kk + 1 < NKSTEP) {
            WSTAGE(kk + 1, 1); XLOAD(kk + 1, xbv);
            asm volatile("s_waitcnt vmcnt(6)" ::: "memory");   // step kk landed
        } else {
            asm volatile("s_waitcnt vmcnt(0)" ::: "memory");
        }
        __builtin_amdgcn_s_barrier();
        COMPUTE(xa, 0);
        __builtin_amdgcn_s_barrier();

        // odd step kk+1: Wlds[1], xbv
        if (kk + 2 < NKSTEP) {
            WSTAGE(kk + 2, 0); XLOAD(kk + 2, xa);
            asm volatile("s_waitcnt vmcnt(6)" ::: "memory");
        } else {
            asm volatile("s_waitcnt vmcnt(0)" ::: "memory");
        }
        __builtin_amdgcn_s_barrier();
        COMPUTE(xbv, 1);
        __builtin_amdgcn_s_barrier();
    }
    #undef XLOAD
    #undef WSTAGE
    #undef COMPUTE

    // Epilogue: lane holds f-col (lo5 + fh*32), 16 pos-rows per frag.
    // gelu + W2-dot in-lane over fh, butterfly over the 32-lane f-group.
    const float* b1e = b1 + e * HFD + fq * 128;
    const float* W2e = W2 + e * HFD + fq * 128;
    const float kInvSqrt2 = 0.70710678118654752f;
    const int f0 = wn * 64 + lo5;
    const float bv0 = b1e[f0],      wv0 = W2e[f0];
    const float bv1 = b1e[f0 + 32], wv1 = W2e[f0 + 32];

    #pragma unroll
    for (int m = 0; m < 2; ++m) {
        #pragma unroll
        for (int q = 0; q < 16; ++q) {
            const float h0 = (m ? acc10[q] : acc00[q]) + bv0;
            const float h1 = (m ? acc11[q] : acc01[q]) + bv1;
            float s = 0.5f * h0 * (1.f + erff(h0 * kInvSqrt2)) * wv0
                    + 0.5f * h1 * (1.f + erff(h1 * kInvSqrt2)) * wv1;
            #pragma unroll
            for (int off = 16; off > 0; off >>= 1)
                s += __shfl_xor(s, off, 64);
            if (lo5 == 0) {
                const int row = wm * 64 + m * 32 + (q & 3) + 8 * (q >> 2) + 4 * hi;
                o_part[wn][row] = s;
            }
        }
    }
    __syncthreads();

    if (tid < nt)
        P4[(size_t)fq * PROWS + cb + pos0 + tid] =
            o_part[0][tid] + o_part[1][tid];
}

// ---------------------------------------------------------------------------
// Combine: out[t] = w0*Σ_fq P4[fq][g0] + w1*Σ_fq P4[fq][g1]. Deterministic.
// ---------------------------------------------------------------------------
__global__ __launch_bounds__(256)
void combine_kernel(const int* __restrict__ inv,
                    const float* __restrict__ P4,
                    const float* __restrict__ wslot,
                    float* __restrict__ out_scores)
{
    const int t = blockIdx.x * 256 + threadIdx.x;
    if (t >= B_TOK) return;
    const int g0 = inv[2 * t];
    const int g1 = inv[2 * t + 1];
    const float s0 = ((P4[g0] + P4[PROWS + g0]) + P4[2 * PROWS + g0])
                   + P4[3 * PROWS + g0];
    const float s1 = ((P4[g1] + P4[PROWS + g1]) + P4[2 * PROWS + g1])
                   + P4[3 * PROWS + g1];
    out_scores[t] = wslot[2 * t] * s0 + wslot[2 * t + 1] * s1;
}

// ---------------------------------------------------------------------------
extern "C" void kernel_launch(void* const* d_in, const int* in_sizes, int n_in,
                              void* d_out, int out_size, void* d_ws, size_t ws_size,
                              hipStream_t stream)
{
    const float* x  = (const float*)d_in[0];
    const float* W1 = (const float*)d_in[1];
    const float* b1 = (const float*)d_in[2];
    const float* W2 = (const float*)d_in[3];
    const float* Wg = (const float*)d_in[4];
    const float* bg = (const float*)d_in[5];

    float* out        = (float*)d_out;
    float* out_scores = out;            // [B, 1]
    float* out_logits = out + B_TOK;    // [B, E]

    char* ws = (char*)d_ws;
    int*            counts = (int*)           (ws + OFF_COUNTS);
    int*            cbase  = (int*)           (ws + OFF_CBASE);
    int*            bucket = (int*)           (ws + OFF_BUCKET);
    float*          wslot  = (float*)         (ws + OFF_WSLOT);
    int*            route  = (int*)           (ws + OFF_ROUTE);
    int*            inv    = (int*)           (ws + OFF_INV);
    float*          WgT    = (float*)         (ws + OFF_WGT);
    float*          P4     = (float*)         (ws + OFF_P4);
    unsigned short* W1q    = (unsigned short*)(ws + OFF_W1Q);
    unsigned short* xgT    = (unsigned short*)(ws + OFF_XGT);

    hipMemsetAsync(counts, 0, NE * sizeof(int), stream);

    wg_transpose_kernel<<<1, 256, 0, stream>>>(Wg, WgT);

    prep_w1_kernel<<<NE * NKSTEP, 256, 0, stream>>>(W1, W1q);

    gate_logits_kernel<<<B_TOK / 64, 256, 0, stream>>>(x, WgT, bg, out_logits,
                                                       wslot, route);

    route_kernel<<<B_TOK / 1024, 1024, 0, stream>>>(route, counts, bucket);

    prefix_kernel<<<1, 64, 0, stream>>>(counts, cbase);

    xgather_kernel<<<NE * (B_TOK * 2 / 64), 256, 0, stream>>>(
        x, bucket, counts, cbase, xgT, inv);

    expert_mfma_kernel<<<NE * 4 * PTMAX, 256, 0, stream>>>(
        xgT, W1q, b1, W2, counts, cbase, P4);

    combine_kernel<<<B_TOK / 256, 256, 0, stream>>>(inv, P4, wslot, out_scores);
}

// Round 14
// 279.854 us; speedup vs baseline: 1.0279x; 1.0279x over previous
//
#include <hip/hip_runtime.h>
#include <math.h>

// Problem constants (match reference)
#define B_TOK 16384
#define H_DIM 2048
#define NE    8
#define TOPK  2
#define HFD   512

#define BK 32
#define NKSTEP (H_DIM / BK)   // 64
#define PTMAX 129
#define PROWS 33792           // padded P rows total (8 experts, 128-padded)

// Workspace layout (bytes)
static constexpr size_t OFF_COUNTS = 0;
static constexpr size_t OFF_CBASE  = 128;
static constexpr size_t OFF_BUCKET = 1024;        // 512 KB
static constexpr size_t OFF_WSLOT  = 525312;      // 128 KB
static constexpr size_t OFF_ROUTE  = 656384;      // 64 KB
static constexpr size_t OFF_INV    = 721920;      // 128 KB
static constexpr size_t OFF_WGT    = 1u << 20;    // 512 KB
static constexpr size_t OFF_P2     = 1572864;     // 2 x 33792 floats = 264 KB
static constexpr size_t OFF_W1H    = 4u << 20;    // 16 MB -> ends 20 MB
static constexpr size_t OFF_XGT    = 20971520;    // 33792 rows * 4 KB = 132 MB
// total ws ~153 MB

typedef short bfrag __attribute__((ext_vector_type(8)));   // 8 bf16 (4 VGPR)
typedef float facc  __attribute__((ext_vector_type(16)));  // 32x32 accum

__device__ inline unsigned short f2bf(float f) {
    union { float f; unsigned u; } v; v.f = f;
    unsigned r = v.u + 0x7FFFu + ((v.u >> 16) & 1u);
    return (unsigned short)(r >> 16);
}
__device__ inline unsigned pack2(float lo, float hi) {
    return (unsigned)f2bf(lo) | ((unsigned)f2bf(hi) << 16);
}

// ---------------------------------------------------------------------------
// Transpose gate weights: Wg [H][E] -> 8 replicas of WgT [E][H].
// ---------------------------------------------------------------------------
__global__ __launch_bounds__(256)
void wg_transpose_kernel(const float* __restrict__ Wg,
                         float* __restrict__ WgT)
{
    const int t = threadIdx.x;
    #pragma unroll
    for (int rep = 0; rep < H_DIM / 256; ++rep) {
        const int h = rep * 256 + t;
        const float4 a = *reinterpret_cast<const float4*>(Wg + (size_t)h * NE);
        const float4 b = *reinterpret_cast<const float4*>(Wg + (size_t)h * NE + 4);
        #pragma unroll
        for (int rr = 0; rr < 8; ++rr) {
            float* W = WgT + (size_t)rr * (NE * H_DIM);
            W[0 * H_DIM + h] = a.x;  W[1 * H_DIM + h] = a.y;
            W[2 * H_DIM + h] = a.z;  W[3 * H_DIM + h] = a.w;
            W[4 * H_DIM + h] = b.x;  W[5 * H_DIM + h] = b.y;
            W[6 * H_DIM + h] = b.z;  W[7 * H_DIM + h] = b.w;
        }
    }
}

// ---------------------------------------------------------------------------
// Prep W1: [E][H][HF] fp32 -> per-(e, f-half) k-slot-major bf16 images:
//   W1h[(e*2+fh)*64 + kstep][slot(4)][f'(256)][j(8)]  (16 KB per image)
// k = kstep*32 + slot*8 + j, f = fh*256 + f'.
// ---------------------------------------------------------------------------
__global__ __launch_bounds__(256)
void prep_w1_kernel(const float* __restrict__ W1,
                    unsigned short* __restrict__ W1h)
{
    const int e     = blockIdx.x >> 6;
    const int kstep = blockIdx.x & 63;
    const int tid   = threadIdx.x;

    const float* src = W1 + ((size_t)e * H_DIM + kstep * BK) * HFD;

    #pragma unroll
    for (int s = 0; s < 4; ++s) {
        #pragma unroll
        for (int fh = 0; fh < 2; ++fh) {
            const int f = fh * 256 + tid;
            float v[8];
            #pragma unroll
            for (int j = 0; j < 8; ++j)
                v[j] = src[(size_t)(s * 8 + j) * HFD + f];   // lane-coalesced
            uint4 p;
            p.x = pack2(v[0], v[1]); p.y = pack2(v[2], v[3]);
            p.z = pack2(v[4], v[5]); p.w = pack2(v[6], v[7]);
            *reinterpret_cast<uint4*>(
                W1h + ((size_t)((e * 2 + fh) * 64 + kstep)) * 8192
                    + (s * 256 + tid) * 8) = p;
        }
    }
}

// ---------------------------------------------------------------------------
// Gate logits: 256 blocks x 64 tokens; WgT staged once into LDS.
// ---------------------------------------------------------------------------
__global__ __launch_bounds__(256)
void gate_logits_kernel(const float* __restrict__ x,
                        const float* __restrict__ WgT,
                        const float* __restrict__ bg,
                        float* __restrict__ out_logits,
                        float* __restrict__ wslot,
                        int*   __restrict__ route)
{
    __shared__ float Wlds[NE * H_DIM];   // 64 KB

    const int tid = threadIdx.x;
    const float* Wsrc = WgT + (size_t)(blockIdx.x & 7) * (NE * H_DIM);
    #pragma unroll
    for (int i = 0; i < (NE * H_DIM) / (256 * 4); ++i) {
        const int idx = (i * 256 + tid) * 4;
        *reinterpret_cast<float4*>(&Wlds[idx]) =
            *reinterpret_cast<const float4*>(Wsrc + idx);
    }
    __syncthreads();

    const int w = tid >> 6, l = tid & 63;
    const int tbase = blockIdx.x * 64 + w * 16;

    for (int pass = 0; pass < 4; ++pass) {
        const int t0 = tbase + pass * 4;
        float acc[4][NE];
        #pragma unroll
        for (int j = 0; j < 4; ++j)
            #pragma unroll
            for (int e = 0; e < NE; ++e) acc[j][e] = 0.f;

        for (int i = 0; i < 8; ++i) {
            const int h = i * 256 + 4 * l;
            float4 xv[4];
            #pragma unroll
            for (int j = 0; j < 4; ++j)
                xv[j] = *reinterpret_cast<const float4*>(
                    x + (size_t)(t0 + j) * H_DIM + h);
            #pragma unroll
            for (int e = 0; e < NE; ++e) {
                const float4 wv = *reinterpret_cast<const float4*>(&Wlds[e * H_DIM + h]);
                #pragma unroll
                for (int j = 0; j < 4; ++j)
                    acc[j][e] += xv[j].x * wv.x + xv[j].y * wv.y
                               + xv[j].z * wv.z + xv[j].w * wv.w;
            }
        }

        #pragma unroll
        for (int j = 0; j < 4; ++j)
            #pragma unroll
            for (int e = 0; e < NE; ++e)
                #pragma unroll
                for (int off = 32; off > 0; off >>= 1)
                    acc[j][e] += __shfl_xor(acc[j][e], off, 64);

        if (l == 0) {
            #pragma unroll
            for (int j = 0; j < 4; ++j) {
                const int tok = t0 + j;
                float lg[NE];
                #pragma unroll
                for (int e = 0; e < NE; ++e) lg[e] = acc[j][e] + bg[e];

                float4* lo = reinterpret_cast<float4*>(out_logits + (size_t)tok * NE);
                lo[0] = make_float4(lg[0], lg[1], lg[2], lg[3]);
                lo[1] = make_float4(lg[4], lg[5], lg[6], lg[7]);

                int i0 = 0; float v0 = lg[0];
                #pragma unroll
                for (int e = 1; e < NE; ++e)
                    if (lg[e] > v0) { v0 = lg[e]; i0 = e; }
                int i1 = -1; float v1 = -3.4e38f;
                #pragma unroll
                for (int e = 0; e < NE; ++e)
                    if (e != i0 && lg[e] > v1) { v1 = lg[e]; i1 = e; }

                const float w0 = 1.f / (1.f + expf(v1 - v0));
                wslot[tok * 2]     = w0;
                wslot[tok * 2 + 1] = 1.f - w0;
                route[tok] = i0 | (i1 << 8);
            }
        }
    }
}

// ---------------------------------------------------------------------------
// Route/bucket: LDS-aggregated histogram; 8 global atomics per block.
// ---------------------------------------------------------------------------
__global__ __launch_bounds__(1024)
void route_kernel(const int* __restrict__ route,
                  int* __restrict__ counts,
                  int* __restrict__ bucket)
{
    __shared__ int lcnt[NE];
    __shared__ int lbase[NE];
    const int tid = threadIdx.x;
    const int tok = blockIdx.x * 1024 + tid;

    if (tid < NE) lcnt[tid] = 0;
    __syncthreads();

    const int rt = route[tok];
    const int i0 = rt & 255;
    const int i1 = rt >> 8;
    const int r0 = atomicAdd(&lcnt[i0], 1);
    const int r1 = atomicAdd(&lcnt[i1], 1);
    __syncthreads();

    if (tid < NE) lbase[tid] = atomicAdd(&counts[tid], lcnt[tid]);
    __syncthreads();

    bucket[i0 * B_TOK + lbase[i0] + r0] = tok * 2;
    bucket[i1 * B_TOK + lbase[i1] + r1] = tok * 2 + 1;
}

// ---------------------------------------------------------------------------
// Prefix: cbase[e] = row base; cpad[e] = count padded to 128.
// ---------------------------------------------------------------------------
__global__ void prefix_kernel(const int* __restrict__ counts,
                              int* __restrict__ cbase)
{
    if (threadIdx.x == 0 && blockIdx.x == 0) {
        int acc = 0;
        for (int e = 0; e < NE; ++e) {
            const int cp = ((counts[e] + 127) >> 7) << 7;
            cbase[e]      = acc;
            cbase[NE + e] = cp;
            acc += cp;
        }
    }
}

// ---------------------------------------------------------------------------
// X gather/transpose: per expert e, 64-pos tile, write k-slot-major image
//   xgT[cb rows][kstep(64)][slot(4)][pos][j(8)]
// elem offset = cb*2048 + ((kstep*4+slot)*cpad + pos)*8. Also writes inv.
// ---------------------------------------------------------------------------
__global__ __launch_bounds__(256)
void xgather_kernel(const float* __restrict__ x,
                    const int* __restrict__ bucket,
                    const int* __restrict__ counts,
                    const int* __restrict__ cbase,
                    unsigned short* __restrict__ xgT,
                    int* __restrict__ inv)
{
    const int e    = blockIdx.x & 7;
    const int tile = blockIdx.x >> 3;
    const int n    = counts[e];
    const int pos0 = tile * 64;
    if (pos0 >= n) return;
    const int cb   = cbase[e];
    const size_t cpad = (size_t)cbase[NE + e];
    const int t = threadIdx.x;

    __shared__ int toks[64];
    __shared__ unsigned short T[8][64][8];

    if (t < 64) {
        const int pos = pos0 + t;
        const int entry = bucket[e * B_TOK + min(pos, n - 1)];
        toks[t] = entry >> 1;
        if (pos < n) inv[entry] = cb + pos;
    }
    __syncthreads();

    const int p = t >> 2;
    const int q = t & 3;
    const float* src = x + (size_t)toks[p] * H_DIM + q * 16;
    unsigned short* dstbase = xgT + (size_t)cb * H_DIM;

    for (int kc = 0; kc < 32; ++kc) {
        const float4 v0 = *reinterpret_cast<const float4*>(src + kc * 64);
        const float4 v1 = *reinterpret_cast<const float4*>(src + kc * 64 + 4);
        const float4 v2 = *reinterpret_cast<const float4*>(src + kc * 64 + 8);
        const float4 v3 = *reinterpret_cast<const float4*>(src + kc * 64 + 12);
        uint4 pa, pb;
        pa.x = pack2(v0.x, v0.y); pa.y = pack2(v0.z, v0.w);
        pa.z = pack2(v1.x, v1.y); pa.w = pack2(v1.z, v1.w);
        pb.x = pack2(v2.x, v2.y); pb.y = pack2(v2.z, v2.w);
        pb.z = pack2(v3.x, v3.y); pb.w = pack2(v3.z, v3.w);
        __syncthreads();
        *reinterpret_cast<uint4*>(&T[q * 2][p][0])     = pa;
        *reinterpret_cast<uint4*>(&T[q * 2 + 1][p][0]) = pb;
        __syncthreads();
        #pragma unroll
        for (int g = 0; g < 2; ++g) {
            const int u   = t + g * 256;
            const int s8  = u >> 6;
            const int pp  = u & 63;
            const int kst = 2 * kc + (s8 >> 2);
            const int sl  = s8 & 3;
            *reinterpret_cast<uint4*>(
                dstbase + ((size_t)(kst * 4 + sl) * cpad + pos0 + pp) * 8) =
                *reinterpret_cast<const uint4*>(&T[s8][pp][0]);
        }
    }
}

// ---------------------------------------------------------------------------
// Expert MFMA (register-streaming, NO LDS / NO barriers in hot loop):
// block = (e, f-half fh (256 f), 128-pos tile); 256 thr / 4 waves;
// wave = (wm pos-half 64, wf f-half 128). acc[2][4] = 128 VGPR.
// Both operands stream straight to VGPRs as coalesced 16 B/lane reads:
//   A = X from xgT k-slot image (32 lanes x 16 B = 512 B contiguous),
//   B = W from W1h k-slot image (contiguous, L2-hot: shared by all
//       pos-tiles of this (e,fh) on the same XCD).
// Free-running waves -> MLP limited only by unroll depth, not barriers.
// ---------------------------------------------------------------------------
__global__ __launch_bounds__(256, 2)
void expert_mfma_kernel(const unsigned short* __restrict__ xgT,
                        const unsigned short* __restrict__ W1h,
                        const float* __restrict__ b1,
                        const float* __restrict__ W2,
                        const int* __restrict__ counts,
                        const int* __restrict__ cbase,
                        float* __restrict__ P2)
{
    const int e  = blockIdx.x & 7;
    const int r  = blockIdx.x >> 3;
    const int fh = r & 1;
    const int pt = r >> 1;
    const int n  = counts[e];
    const int pos0 = pt * 128;
    if (pos0 >= n) return;
    const int nt = min(128, n - pos0);
    const int cb = cbase[e];
    const size_t cpad = (size_t)cbase[NE + e];

    __shared__ float o_part[2][128];   // [wf][pos]  1 KB

    const int tid = threadIdx.x;
    const int w   = tid >> 6;
    const int l   = tid & 63;
    const int lo5 = l & 31;
    const int hi  = l >> 5;
    const int wm  = w & 1;      // pos half (64 rows)
    const int wf  = w >> 1;     // f half of 256 (128 cols)

    const unsigned short* Wimg = W1h + (size_t)((e * 2 + fh) * 64) * 8192;
    const unsigned short* xg_e = xgT + (size_t)cb * H_DIM;

    const size_t posm0 = (size_t)pos0 + wm * 64 + lo5;
    const size_t posm1 = posm0 + 32;

    facc acc[2][4];   // [m][fcol]
    #pragma unroll
    for (int m = 0; m < 2; ++m)
        #pragma unroll
        for (int fc = 0; fc < 4; ++fc)
            #pragma unroll
            for (int q = 0; q < 16; ++q) acc[m][fc][q] = 0.f;

    #pragma unroll 4
    for (int kk = 0; kk < NKSTEP; ++kk) {
        // X A-frags: [m][c], slot = c*2 + hi
        bfrag xf[2][2];
        #pragma unroll
        for (int c = 0; c < 2; ++c) {
            xf[0][c] = *reinterpret_cast<const bfrag*>(
                xg_e + ((size_t)(kk * 4 + c * 2 + hi) * cpad + posm0) * 8);
            xf[1][c] = *reinterpret_cast<const bfrag*>(
                xg_e + ((size_t)(kk * 4 + c * 2 + hi) * cpad + posm1) * 8);
        }
        // W B-frags: [fc][c], f' = wf*128 + fc*32 + lo5
        bfrag wfr[4][2];
        const unsigned short* wk = Wimg + (size_t)kk * 8192;
        #pragma unroll
        for (int fc = 0; fc < 4; ++fc)
            #pragma unroll
            for (int c = 0; c < 2; ++c)
                wfr[fc][c] = *reinterpret_cast<const bfrag*>(
                    wk + ((c * 2 + hi) * 256 + wf * 128 + fc * 32 + lo5) * 8);

        #pragma unroll
        for (int c = 0; c < 2; ++c)
            #pragma unroll
            for (int m = 0; m < 2; ++m)
                #pragma unroll
                for (int fc = 0; fc < 4; ++fc)
                    acc[m][fc] = __builtin_amdgcn_mfma_f32_32x32x16_bf16(
                        xf[m][c], wfr[fc][c], acc[m][fc], 0, 0, 0);
    }

    // Epilogue: lane holds f-col; gelu + W2 dot in-lane over 4 f-cols,
    // butterfly over the 32-lane f-group (rows differ by hi: +4*hi).
    const float* b1e = b1 + e * HFD + fh * 256;
    const float* W2e = W2 + e * HFD + fh * 256;
    const float kInvSqrt2 = 0.70710678118654752f;
    float bv[4], wv[4];
    #pragma unroll
    for (int fc = 0; fc < 4; ++fc) {
        const int f = wf * 128 + fc * 32 + lo5;
        bv[fc] = b1e[f];
        wv[fc] = W2e[f];
    }

    #pragma unroll
    for (int m = 0; m < 2; ++m) {
        #pragma unroll
        for (int q = 0; q < 16; ++q) {
            float s = 0.f;
            #pragma unroll
            for (int fc = 0; fc < 4; ++fc) {
                const float h = acc[m][fc][q] + bv[fc];
                s += 0.5f * h * (1.f + erff(h * kInvSqrt2)) * wv[fc];
            }
            #pragma unroll
            for (int off = 16; off > 0; off >>= 1)
                s += __shfl_xor(s, off, 64);
            if (lo5 == 0) {
                const int row = wm * 64 + m * 32 + (q & 3) + 8 * (q >> 2) + 4 * hi;
                o_part[wf][row] = s;
            }
        }
    }
    __syncthreads();

    if (tid < nt)
        P2[(size_t)fh * PROWS + cb + pos0 + tid] =
            o_part[0][tid] + o_part[1][tid];
}

// ---------------------------------------------------------------------------
// Combine: out[t] = w0*(P2[0][g0]+P2[1][g0]) + w1*(...). Deterministic.
// ---------------------------------------------------------------------------
__global__ __launch_bounds__(256)
void combine_kernel(const int* __restrict__ inv,
                    const float* __restrict__ P2,
                    const float* __restrict__ wslot,
                    float* __restrict__ out_scores)
{
    const int t = blockIdx.x * 256 + threadIdx.x;
    if (t >= B_TOK) return;
    const int g0 = inv[2 * t];
    const int g1 = inv[2 * t + 1];
    const float s0 = P2[g0] + P2[PROWS + g0];
    const float s1 = P2[g1] + P2[PROWS + g1];
    out_scores[t] = wslot[2 * t] * s0 + wslot[2 * t + 1] * s1;
}

// ---------------------------------------------------------------------------
extern "C" void kernel_launch(void* const* d_in, const int* in_sizes, int n_in,
                              void* d_out, int out_size, void* d_ws, size_t ws_size,
                              hipStream_t stream)
{
    const float* x  = (const float*)d_in[0];
    const float* W1 = (const float*)d_in[1];
    const float* b1 = (const float*)d_in[2];
    const float* W2 = (const float*)d_in[3];
    const float* Wg = (const float*)d_in[4];
    const float* bg = (const float*)d_in[5];

    float* out        = (float*)d_out;
    float* out_scores = out;            // [B, 1]
    float* out_logits = out + B_TOK;    // [B, E]

    char* ws = (char*)d_ws;
    int*            counts = (int*)           (ws + OFF_COUNTS);
    int*            cbase  = (int*)           (ws + OFF_CBASE);
    int*            bucket = (int*)           (ws + OFF_BUCKET);
    float*          wslot  = (float*)         (ws + OFF_WSLOT);
    int*            route  = (int*)           (ws + OFF_ROUTE);
    int*            inv    = (int*)           (ws + OFF_INV);
    float*          WgT    = (float*)         (ws + OFF_WGT);
    float*          P2     = (float*)         (ws + OFF_P2);
    unsigned short* W1h    = (unsigned short*)(ws + OFF_W1H);
    unsigned short* xgT    = (unsigned short*)(ws + OFF_XGT);

    hipMemsetAsync(counts, 0, NE * sizeof(int), stream);

    wg_transpose_kernel<<<1, 256, 0, stream>>>(Wg, WgT);

    prep_w1_kernel<<<NE * NKSTEP, 256, 0, stream>>>(W1, W1h);

    gate_logits_kernel<<<B_TOK / 64, 256, 0, stream>>>(x, WgT, bg, out_logits,
                                                       wslot, route);

    route_kernel<<<B_TOK / 1024, 1024, 0, stream>>>(route, counts, bucket);

    prefix_kernel<<<1, 64, 0, stream>>>(counts, cbase);

    xgather_kernel<<<NE * (B_TOK * 2 / 64), 256, 0, stream>>>(
        x, bucket, counts, cbase, xgT, inv);

    expert_mfma_kernel<<<NE * 2 * PTMAX, 256, 0, stream>>>(
        xgT, W1h, b1, W2, counts, cbase, P2);

    combine_kernel<<<B_TOK / 256, 256, 0, stream>>>(inv, P2, wslot, out_scores);
}